// Round 2
// baseline (544.462 us; speedup 1.0000x reference)
//
#include <hip/hip_runtime.h>
#include <hip/hip_bf16.h>

// Problem constants
static constexpr int Bn = 8, Cn = 128, Hn = 64, Wn = 64, Con = 128;
static constexpr int KKn = 9, DGn = 2, Cgn = 64;
static constexpr int HOn = 64, WOn = 64;
static constexpr int PITCH = 72;     // bf16 row pitch (pad 64 -> 72: 36-bank stride, 2-way max w/ b128)

typedef short short8 __attribute__((ext_vector_type(8)));
typedef float f32x4  __attribute__((ext_vector_type(4)));

__device__ __forceinline__ unsigned short f2bf(float f) {
    unsigned u = __float_as_uint(f);
    u += 0x7fff + ((u >> 16) & 1);          // round-to-nearest-even
    return (unsigned short)(u >> 16);
}

// ---------------------------------------------------------------------------
// Kernel 0: main weight [Co,C,3,3] fp32 -> bf16, layout wt[gk][oc][c] with
// c padded to PITCH=72 (pad = 0). 18*128*72 = 165888 elems, grid 648x256.
// ---------------------------------------------------------------------------
__global__ __launch_bounds__(256) void wt_transpose(const float* __restrict__ w,
                                                    unsigned short* __restrict__ wt) {
    int e  = blockIdx.x * 256 + threadIdx.x;     // [0, 165888)
    int gk = e / (128 * PITCH);
    int r  = e - gk * (128 * PITCH);
    int oc = r / PITCH;
    int c  = r - oc * PITCH;
    int g  = gk / 9, k = gk - g * 9;
    float v = (c < Cgn) ? w[((size_t)oc * Cn + g * Cgn + c) * KKn + k] : 0.f;
    wt[e] = f2bf(v);
}

// ---------------------------------------------------------------------------
// Kernel 1: grouped offset conv. One block per (b, conv-group, 4-row strip).
// x rows staged in LDS (16-channel chunks); each thread keeps 27 accumulators
// so every x value is reused across all 27 output channels of the group.
// Weights are wave-uniform -> scalar loads. grid (16,2,8), block 256.
// ---------------------------------------------------------------------------
__global__ __launch_bounds__(256) void offset_conv(const float* __restrict__ x,
                                                   const float* __restrict__ ow,
                                                   const float* __restrict__ ob,
                                                   float* __restrict__ om) {
    __shared__ float s_x[16 * 8 * 64];           // 32 KB: [c][row][col]
    const int t  = threadIdx.x;
    const int wo = t & 63;
    const int hl = t >> 6;                       // 0..3
    const int ho0 = blockIdx.x * 4;
    const int cg  = blockIdx.y;                  // conv group
    const int b   = blockIdx.z;
    const int ho  = ho0 + hl;

    float acc[27];
#pragma unroll
    for (int oc = 0; oc < 27; ++oc) acc[oc] = ob[cg * 27 + oc];

    for (int cc = 0; cc < 4; ++cc) {             // channel chunks of 16
        __syncthreads();
        // ---- stage 16 channels x 8 rows (ho0-2 .. ho0+5), zero-padded ----
#pragma unroll
        for (int i = 0; i < 8; ++i) {
            int e = t + i * 256;                 // float4 id, [0,2048)
            int c = e >> 7;
            int r = (e >> 4) & 7;
            int q = e & 15;
            int iy = ho0 - 2 + r;
            float4 v = {0.f, 0.f, 0.f, 0.f};
            if (iy >= 0 && iy < Hn)
                v = *(const float4*)&x[(((size_t)b * Cn + cg * Cgn + cc * 16 + c) * Hn + iy) * Wn + q * 4];
            *(float4*)&s_x[e * 4] = v;
        }
        __syncthreads();

        for (int c = 0; c < 16; ++c) {
            float xv[9];
#pragma unroll
            for (int ky = 0; ky < 3; ++ky)
#pragma unroll
                for (int kx = 0; kx < 3; ++kx) {
                    int ix = wo - 2 + 2 * kx;
                    xv[ky * 3 + kx] = (ix >= 0 && ix < Wn)
                        ? s_x[(c * 8 + hl + 2 * ky) * 64 + ix] : 0.f;
                }
            const float* wp = ow + ((size_t)(cg * 27) * Cgn + cc * 16 + c) * KKn;
#pragma unroll 9
            for (int oc = 0; oc < 27; ++oc) {
                const float* wq = wp + (size_t)oc * Cgn * KKn;
#pragma unroll
                for (int k = 0; k < 9; ++k)
                    acc[oc] = fmaf(xv[k], wq[k], acc[oc]);
            }
        }
    }
#pragma unroll
    for (int oc = 0; oc < 27; ++oc)
        om[(((size_t)b * 54 + cg * 27 + oc) * HOn + ho) * WOn + wo] = acc[oc];
}

// ---------------------------------------------------------------------------
// Kernel 2: fused deformable gather + bf16 MFMA contraction.
// Block = (b, ho): 64 positions x 128 oc, K = 18 gk x 64 c.
// Per gk: gather val[pos][c] bf16 tile (mask+bilinear premultiplied, fp32
// math, bf16 store), stage w[oc][c] slab, 2 K-steps of mfma_f32_16x16x32_bf16.
// Wave wv covers oc [wv*32, wv*32+32): 4 m-tiles x 2 n-tiles, acc 32 VGPRs.
// LDS: 9216 (val) + 18432 (w) + 18432 (cw) + 4608 (pk) = 50688 -> 3 blk/CU.
// ---------------------------------------------------------------------------
__global__ __launch_bounds__(256, 3) void dcn_main(const float* __restrict__ x,
                                                   const float* __restrict__ om,
                                                   const unsigned short* __restrict__ wtp,
                                                   float* __restrict__ out) {
    __shared__ __align__(16) unsigned short s_val[64 * PITCH];   // [pos][c]
    __shared__ __align__(16) unsigned short s_w[128 * PITCH];    // [oc][c]
    __shared__ float4 s_cw[18][64];
    __shared__ int    s_pk[18][64];

    const int t  = threadIdx.x;
    const int ho = blockIdx.x;
    const int b  = blockIdx.y;

    // ---- sampling params for all (g,k,wo) of this row ----
    for (int e = t; e < 18 * 64; e += 256) {
        int wo = e & 63;
        int gk = e >> 6;
        int g  = gk / 9, k = gk - g * 9;
        int ky = k / 3,  kx = k - ky * 3;
        const float* omb = om + (size_t)b * 54 * (HOn * WOn) + ho * WOn + wo;
        float offy = omb[(g * 18 + k * 2 + 0) * (HOn * WOn)];
        float offx = omb[(g * 18 + k * 2 + 1) * (HOn * WOn)];
        float mk   = omb[(36 + g * 9 + k) * (HOn * WOn)];
        mk = 2.0f / (1.0f + __expf(-mk));

        float py = offy + (float)(ky * 2 + ho - 2);
        float px = offx + (float)(kx * 2 + wo - 2);
        float fy = floorf(py), fx = floorf(px);
        int   y0 = (int)fy,    x0 = (int)fx;
        float wy = py - fy,    wx = px - fx;

        bool vy0 = (y0 >= 0) & (y0 < Hn);
        bool vy1 = (y0 + 1 >= 0) & (y0 + 1 < Hn);
        bool vx0 = (x0 >= 0) & (x0 < Wn);
        bool vx1 = (x0 + 1 >= 0) & (x0 + 1 < Wn);
        float4 cw;
        cw.x = (vy0 & vx0) ? (1.f - wy) * (1.f - wx) * mk : 0.f;
        cw.y = (vy0 & vx1) ? (1.f - wy) * wx * mk : 0.f;
        cw.z = (vy1 & vx0) ? wy * (1.f - wx) * mk : 0.f;
        cw.w = (vy1 & vx1) ? wy * wx * mk : 0.f;

        int y0c = min(max(y0, 0), Hn - 1);
        int y1c = min(max(y0 + 1, 0), Hn - 1);
        int x0c = min(max(x0, 0), Wn - 1);
        int x1c = min(max(x0 + 1, 0), Wn - 1);
        s_cw[gk][wo] = cw;
        s_pk[gk][wo] = y0c | (y1c << 8) | (x0c << 16) | (x1c << 24);
    }
    __syncthreads();

    const int lane = t & 63;
    const int wv   = t >> 6;                 // wave id 0..3
    const int lr   = lane & 15;              // MFMA row/col part
    const int lk   = (lane >> 4) * 8;        // MFMA k offset

    f32x4 acc[4][2];
#pragma unroll
    for (int mt = 0; mt < 4; ++mt)
#pragma unroll
        for (int nt = 0; nt < 2; ++nt) acc[mt][nt] = (f32x4){0.f, 0.f, 0.f, 0.f};

    for (int gk = 0; gk < 18; ++gk) {
        if (gk) __syncthreads();

        // ---- weight slab prefetch (global -> regs, written to LDS below) ----
        const int4* wsrc = (const int4*)(wtp + (size_t)gk * 128 * PITCH);
        int4 wreg[5];
#pragma unroll
        for (int i = 0; i < 4; ++i) wreg[i] = wsrc[t + i * 256];
        if (t < 128) wreg[4] = wsrc[t + 1024];

        // ---- gather val tile: lane = pos, this wave covers 16 channels ----
        {
            const int g = gk / 9;
            float4 cw = s_cw[gk][lane];
            int pk = s_pk[gk][lane];
            int y0c = pk & 255, y1c = (pk >> 8) & 255;
            int x0c = (pk >> 16) & 255, x1c = (pk >> 24) & 255;
            int i00 = y0c * Wn + x0c, i01 = y0c * Wn + x1c;
            int i10 = y1c * Wn + x0c, i11 = y1c * Wn + x1c;
            const float* xb = x + ((size_t)(b * Cn + g * Cgn + wv * 16)) * (Hn * Wn);
#pragma unroll
            for (int s = 0; s < 2; ++s) {
                short8 hv;
#pragma unroll
                for (int i = 0; i < 8; ++i) {
                    const float* xc = xb + (size_t)(s * 8 + i) * (Hn * Wn);
                    float v = cw.x * xc[i00] + cw.y * xc[i01] +
                              cw.z * xc[i10] + cw.w * xc[i11];
                    hv[i] = (short)f2bf(v);
                }
                *(short8*)&s_val[lane * PITCH + wv * 16 + s * 8] = hv;
            }
        }
        // ---- commit weight slab to LDS ----
        {
            int4* wdst = (int4*)s_w;
#pragma unroll
            for (int i = 0; i < 4; ++i) wdst[t + i * 256] = wreg[i];
            if (t < 128) wdst[t + 1024] = wreg[4];
        }
        __syncthreads();

        // ---- 2 K-steps of MFMA over the 64-channel tile ----
#pragma unroll
        for (int ks = 0; ks < 2; ++ks) {
            const int k0 = ks * 32;
            short8 af[4], bf[2];
#pragma unroll
            for (int mt = 0; mt < 4; ++mt)
                af[mt] = *(const short8*)&s_val[(mt * 16 + lr) * PITCH + k0 + lk];
#pragma unroll
            for (int nt = 0; nt < 2; ++nt)
                bf[nt] = *(const short8*)&s_w[(wv * 32 + nt * 16 + lr) * PITCH + k0 + lk];
#pragma unroll
            for (int mt = 0; mt < 4; ++mt)
#pragma unroll
                for (int nt = 0; nt < 2; ++nt)
                    acc[mt][nt] = __builtin_amdgcn_mfma_f32_16x16x32_bf16(
                        af[mt], bf[nt], acc[mt][nt], 0, 0, 0);
        }
    }

    // ---- epilogue: D col = oc (lane&15), row = pos ((lane>>4)*4 + reg) ----
#pragma unroll
    for (int mt = 0; mt < 4; ++mt)
#pragma unroll
        for (int nt = 0; nt < 2; ++nt) {
            int oc = wv * 32 + nt * 16 + lr;
            int p0 = mt * 16 + (lane >> 4) * 4;
            float4 v = {acc[mt][nt][0], acc[mt][nt][1], acc[mt][nt][2], acc[mt][nt][3]};
            *(float4*)&out[(((size_t)b * Con + oc) * HOn + ho) * WOn + p0] = v;
        }
}

// ---------------------------------------------------------------------------
extern "C" void kernel_launch(void* const* d_in, const int* in_sizes, int n_in,
                              void* d_out, int out_size, void* d_ws, size_t ws_size,
                              hipStream_t stream) {
    const float* x  = (const float*)d_in[0];   // [8,128,64,64]
    const float* ow = (const float*)d_in[1];   // [54,64,3,3]
    const float* ob = (const float*)d_in[2];   // [54]
    const float* w  = (const float*)d_in[3];   // [128,128,3,3]
    float* out = (float*)d_out;                // [8,128,64,64]

    // workspace: om fp32 (8*54*64*64 = 7077888 B) | wt bf16 padded (331776 B)
    float* om = (float*)d_ws;
    unsigned short* wt = (unsigned short*)((char*)d_ws + 7077888);

    hipLaunchKernelGGL(wt_transpose, dim3(648), dim3(256), 0, stream, w, wt);
    hipLaunchKernelGGL(offset_conv, dim3(16, 2, 8), dim3(256), 0, stream,
                       x, ow, ob, om);
    hipLaunchKernelGGL(dcn_main, dim3(64, 8), dim3(256), 0, stream,
                       x, om, wt, out);
}

// Round 3
// 257.852 us; speedup vs baseline: 2.1115x; 2.1115x over previous
//
#include <hip/hip_runtime.h>
#include <hip/hip_bf16.h>

// Problem constants
static constexpr int Bn = 8, Cn = 128, Hn = 64, Wn = 64, Con = 128;
static constexpr int KKn = 9, DGn = 2, Cgn = 64;
static constexpr int HOn = 64, WOn = 64;
static constexpr int PITCH = 72;     // bf16 row pitch for MFMA LDS tiles

typedef short short8 __attribute__((ext_vector_type(8)));
typedef float f32x4  __attribute__((ext_vector_type(4)));

__device__ __forceinline__ unsigned short f2bf(float f) {
    unsigned u = __float_as_uint(f);
    u += 0x7fff + ((u >> 16) & 1);          // round-to-nearest-even
    return (unsigned short)(u >> 16);
}
__device__ __forceinline__ float bf2f(unsigned short h) {
    return __uint_as_float(((unsigned)h) << 16);
}

// ---------------------------------------------------------------------------
// Kernel 0: main weight [Co,C,3,3] fp32 -> bf16, layout wt[gk][oc][c] with
// c padded to PITCH=72 (pad = 0). 18*128*72 = 165888 elems, grid 648x256.
// ---------------------------------------------------------------------------
__global__ __launch_bounds__(256) void wt_transpose(const float* __restrict__ w,
                                                    unsigned short* __restrict__ wt) {
    int e  = blockIdx.x * 256 + threadIdx.x;     // [0, 165888)
    int gk = e / (128 * PITCH);
    int r  = e - gk * (128 * PITCH);
    int oc = r / PITCH;
    int c  = r - oc * PITCH;
    int g  = gk / 9, k = gk - g * 9;
    float v = (c < Cgn) ? w[((size_t)oc * Cn + g * Cgn + c) * KKn + k] : 0.f;
    wt[e] = f2bf(v);
}

// ---------------------------------------------------------------------------
// Kernel 0b: pack offset weights for SGPR-friendly access.
// owp[tr][c][28]: triple tr (oc = tr*3..tr*3+2), q = j*9+k (27 used, 1 pad).
// 18*64*28 = 32256 elems, grid 126x256.
// ---------------------------------------------------------------------------
__global__ __launch_bounds__(256) void ow_pack(const float* __restrict__ ow,
                                               float* __restrict__ owp) {
    int e  = blockIdx.x * 256 + threadIdx.x;     // [0, 32256)
    if (e >= 18 * 64 * 28) return;
    int tr = e / (64 * 28);
    int r  = e - tr * (64 * 28);
    int c  = r / 28;
    int q  = r - c * 28;
    float v = 0.f;
    if (q < 27) {
        int j = q / 9, k = q - j * 9;
        int oc = tr * 3 + j;
        v = ow[((size_t)oc * Cgn + c) * KKn + k];
    }
    owp[e] = v;
}

// ---------------------------------------------------------------------------
// Kernel 1: grouped offset conv, 3 oc per block (27 uniform weights per
// c-iter -> fits SGPRs; s_load_dwordx8 batches). 2304 blocks (~9/CU) for TLP.
// x reads coalesced along wo, predicated for padding. Output bf16.
// grid (16, 18, 8), block 256 (4 ho rows).
// ---------------------------------------------------------------------------
__global__ __launch_bounds__(256) void offset_conv(const float* __restrict__ x,
                                                   const float* __restrict__ owp,
                                                   const float* __restrict__ ob,
                                                   unsigned short* __restrict__ om) {
    const int t  = threadIdx.x;
    const int wo = t & 63;
    const int ho = blockIdx.x * 4 + (t >> 6);
    const int tr = blockIdx.y;                   // oc triple 0..17
    const int b  = blockIdx.z;
    const int g  = tr / 9;                       // conv group

    const float* wp = owp + (size_t)tr * 64 * 28;
    float acc0 = ob[tr * 3 + 0];
    float acc1 = ob[tr * 3 + 1];
    float acc2 = ob[tr * 3 + 2];

    const float* xb = x + ((size_t)b * Cn + g * Cgn) * (Hn * Wn);
    const int iy0 = ho - 2, iy1 = ho, iy2 = ho + 2;
    const bool vy0 = iy0 >= 0, vy2 = iy2 < Hn;
    const int ix0 = wo - 2, ix1 = wo, ix2 = wo + 2;
    const bool vx0 = ix0 >= 0, vx2 = ix2 < Wn;

#pragma unroll 2
    for (int c = 0; c < Cgn; ++c) {
        const float* xc = xb + (size_t)c * (Hn * Wn);
        const float* r0 = xc + iy0 * Wn;
        const float* r1 = xc + iy1 * Wn;
        const float* r2 = xc + iy2 * Wn;
        float xv[9];
        xv[0] = (vy0 & vx0) ? r0[ix0] : 0.f;
        xv[1] = vy0         ? r0[ix1] : 0.f;
        xv[2] = (vy0 & vx2) ? r0[ix2] : 0.f;
        xv[3] = vx0         ? r1[ix0] : 0.f;
        xv[4] =               r1[ix1];
        xv[5] = vx2         ? r1[ix2] : 0.f;
        xv[6] = (vy2 & vx0) ? r2[ix0] : 0.f;
        xv[7] = vy2         ? r2[ix1] : 0.f;
        xv[8] = (vy2 & vx2) ? r2[ix2] : 0.f;
        const float* wc = wp + c * 28;
#pragma unroll
        for (int k = 0; k < 9; ++k) acc0 = fmaf(xv[k], wc[k], acc0);
#pragma unroll
        for (int k = 0; k < 9; ++k) acc1 = fmaf(xv[k], wc[9 + k], acc1);
#pragma unroll
        for (int k = 0; k < 9; ++k) acc2 = fmaf(xv[k], wc[18 + k], acc2);
    }
    size_t o = (((size_t)b * 54 + tr * 3) * HOn + ho) * WOn + wo;
    om[o]                    = f2bf(acc0);
    om[o + (size_t)HOn*WOn]  = f2bf(acc1);
    om[o + (size_t)2*HOn*WOn] = f2bf(acc2);
}

// ---------------------------------------------------------------------------
// Kernel 2: fused deformable gather + bf16 MFMA contraction (unchanged from
// R2 except om is now bf16).
// Block = (b, ho): 64 positions x 128 oc, K = 18 gk x 64 c.
// LDS: 9216 (val) + 18432 (w) + 18432 (cw) + 4608 (pk) = 50688 -> 3 blk/CU.
// ---------------------------------------------------------------------------
__global__ __launch_bounds__(256, 3) void dcn_main(const float* __restrict__ x,
                                                   const unsigned short* __restrict__ om,
                                                   const unsigned short* __restrict__ wtp,
                                                   float* __restrict__ out) {
    __shared__ __align__(16) unsigned short s_val[64 * PITCH];   // [pos][c]
    __shared__ __align__(16) unsigned short s_w[128 * PITCH];    // [oc][c]
    __shared__ float4 s_cw[18][64];
    __shared__ int    s_pk[18][64];

    const int t  = threadIdx.x;
    const int ho = blockIdx.x;
    const int b  = blockIdx.y;

    // ---- sampling params for all (g,k,wo) of this row ----
    for (int e = t; e < 18 * 64; e += 256) {
        int wo = e & 63;
        int gk = e >> 6;
        int g  = gk / 9, k = gk - g * 9;
        int ky = k / 3,  kx = k - ky * 3;
        const unsigned short* omb = om + (size_t)b * 54 * (HOn * WOn) + ho * WOn + wo;
        float offy = bf2f(omb[(g * 18 + k * 2 + 0) * (HOn * WOn)]);
        float offx = bf2f(omb[(g * 18 + k * 2 + 1) * (HOn * WOn)]);
        float mk   = bf2f(omb[(36 + g * 9 + k) * (HOn * WOn)]);
        mk = 2.0f / (1.0f + __expf(-mk));

        float py = offy + (float)(ky * 2 + ho - 2);
        float px = offx + (float)(kx * 2 + wo - 2);
        float fy = floorf(py), fx = floorf(px);
        int   y0 = (int)fy,    x0 = (int)fx;
        float wy = py - fy,    wx = px - fx;

        bool vy0 = (y0 >= 0) & (y0 < Hn);
        bool vy1 = (y0 + 1 >= 0) & (y0 + 1 < Hn);
        bool vx0 = (x0 >= 0) & (x0 < Wn);
        bool vx1 = (x0 + 1 >= 0) & (x0 + 1 < Wn);
        float4 cw;
        cw.x = (vy0 & vx0) ? (1.f - wy) * (1.f - wx) * mk : 0.f;
        cw.y = (vy0 & vx1) ? (1.f - wy) * wx * mk : 0.f;
        cw.z = (vy1 & vx0) ? wy * (1.f - wx) * mk : 0.f;
        cw.w = (vy1 & vx1) ? wy * wx * mk : 0.f;

        int y0c = min(max(y0, 0), Hn - 1);
        int y1c = min(max(y0 + 1, 0), Hn - 1);
        int x0c = min(max(x0, 0), Wn - 1);
        int x1c = min(max(x0 + 1, 0), Wn - 1);
        s_cw[gk][wo] = cw;
        s_pk[gk][wo] = y0c | (y1c << 8) | (x0c << 16) | (x1c << 24);
    }
    __syncthreads();

    const int lane = t & 63;
    const int wv   = t >> 6;                 // wave id 0..3
    const int lr   = lane & 15;              // MFMA row/col part
    const int lk   = (lane >> 4) * 8;        // MFMA k offset

    f32x4 acc[4][2];
#pragma unroll
    for (int mt = 0; mt < 4; ++mt)
#pragma unroll
        for (int nt = 0; nt < 2; ++nt) acc[mt][nt] = (f32x4){0.f, 0.f, 0.f, 0.f};

    for (int gk = 0; gk < 18; ++gk) {
        if (gk) __syncthreads();

        // ---- weight slab prefetch (global -> regs, written to LDS below) ----
        const int4* wsrc = (const int4*)(wtp + (size_t)gk * 128 * PITCH);
        int4 wreg[5];
#pragma unroll
        for (int i = 0; i < 4; ++i) wreg[i] = wsrc[t + i * 256];
        if (t < 128) wreg[4] = wsrc[t + 1024];

        // ---- gather val tile: lane = pos, this wave covers 16 channels ----
        {
            const int g = gk / 9;
            float4 cw = s_cw[gk][lane];
            int pk = s_pk[gk][lane];
            int y0c = pk & 255, y1c = (pk >> 8) & 255;
            int x0c = (pk >> 16) & 255, x1c = (pk >> 24) & 255;
            int i00 = y0c * Wn + x0c, i01 = y0c * Wn + x1c;
            int i10 = y1c * Wn + x0c, i11 = y1c * Wn + x1c;
            const float* xb = x + ((size_t)(b * Cn + g * Cgn + wv * 16)) * (Hn * Wn);
#pragma unroll
            for (int s = 0; s < 2; ++s) {
                short8 hv;
#pragma unroll
                for (int i = 0; i < 8; ++i) {
                    const float* xc = xb + (size_t)(s * 8 + i) * (Hn * Wn);
                    float v = cw.x * xc[i00] + cw.y * xc[i01] +
                              cw.z * xc[i10] + cw.w * xc[i11];
                    hv[i] = (short)f2bf(v);
                }
                *(short8*)&s_val[lane * PITCH + wv * 16 + s * 8] = hv;
            }
        }
        // ---- commit weight slab to LDS ----
        {
            int4* wdst = (int4*)s_w;
#pragma unroll
            for (int i = 0; i < 4; ++i) wdst[t + i * 256] = wreg[i];
            if (t < 128) wdst[t + 1024] = wreg[4];
        }
        __syncthreads();

        // ---- 2 K-steps of MFMA over the 64-channel tile ----
#pragma unroll
        for (int ks = 0; ks < 2; ++ks) {
            const int k0 = ks * 32;
            short8 af[4], bf[2];
#pragma unroll
            for (int mt = 0; mt < 4; ++mt)
                af[mt] = *(const short8*)&s_val[(mt * 16 + lr) * PITCH + k0 + lk];
#pragma unroll
            for (int nt = 0; nt < 2; ++nt)
                bf[nt] = *(const short8*)&s_w[(wv * 32 + nt * 16 + lr) * PITCH + k0 + lk];
#pragma unroll
            for (int mt = 0; mt < 4; ++mt)
#pragma unroll
                for (int nt = 0; nt < 2; ++nt)
                    acc[mt][nt] = __builtin_amdgcn_mfma_f32_16x16x32_bf16(
                        af[mt], bf[nt], acc[mt][nt], 0, 0, 0);
        }
    }

    // ---- epilogue: D col = oc (lane&15), row = pos ((lane>>4)*4 + reg) ----
#pragma unroll
    for (int mt = 0; mt < 4; ++mt)
#pragma unroll
        for (int nt = 0; nt < 2; ++nt) {
            int oc = wv * 32 + nt * 16 + lr;
            int p0 = mt * 16 + (lane >> 4) * 4;
            float4 v = {acc[mt][nt][0], acc[mt][nt][1], acc[mt][nt][2], acc[mt][nt][3]};
            *(float4*)&out[(((size_t)b * Con + oc) * HOn + ho) * WOn + p0] = v;
        }
}

// ---------------------------------------------------------------------------
extern "C" void kernel_launch(void* const* d_in, const int* in_sizes, int n_in,
                              void* d_out, int out_size, void* d_ws, size_t ws_size,
                              hipStream_t stream) {
    const float* x  = (const float*)d_in[0];   // [8,128,64,64]
    const float* ow = (const float*)d_in[1];   // [54,64,3,3]
    const float* ob = (const float*)d_in[2];   // [54]
    const float* w  = (const float*)d_in[3];   // [128,128,3,3]
    float* out = (float*)d_out;                // [8,128,64,64]

    // workspace: om bf16 (3538944 B) | wt bf16 (331776 B) | owp f32 (129024 B)
    unsigned short* om = (unsigned short*)d_ws;
    unsigned short* wt = (unsigned short*)((char*)d_ws + 3538944);
    float* owp = (float*)((char*)d_ws + 3538944 + 331776);

    hipLaunchKernelGGL(wt_transpose, dim3(648), dim3(256), 0, stream, w, wt);
    hipLaunchKernelGGL(ow_pack, dim3(126), dim3(256), 0, stream, ow, owp);
    hipLaunchKernelGGL(offset_conv, dim3(16, 18, 8), dim3(256), 0, stream,
                       x, owp, ob, om);
    hipLaunchKernelGGL(dcn_main, dim3(64, 8), dim3(256), 0, stream,
                       x, om, wt, out);
}

// Round 5
// 257.830 us; speedup vs baseline: 2.1117x; 1.0001x over previous
//
#include <hip/hip_runtime.h>
#include <hip/hip_bf16.h>

// Problem constants
static constexpr int Bn = 8, Cn = 128, Hn = 64, Wn = 64, Con = 128;
static constexpr int KKn = 9, DGn = 2, Cgn = 64;
static constexpr int HOn = 64, WOn = 64;
static constexpr int PITCH = 72;     // bf16 row pitch for MFMA LDS tiles

typedef short short8 __attribute__((ext_vector_type(8)));
typedef float f32x4  __attribute__((ext_vector_type(4)));

__device__ __forceinline__ unsigned short f2bf(float f) {
    unsigned u = __float_as_uint(f);
    u += 0x7fff + ((u >> 16) & 1);          // round-to-nearest-even
    return (unsigned short)(u >> 16);
}
__device__ __forceinline__ float bf2f(unsigned short h) {
    return __uint_as_float(((unsigned)h) << 16);
}

// ---------------------------------------------------------------------------
// Kernel 0: main weight [Co,C,3,3] fp32 -> bf16, layout wt[gk][oc][c] with
// c padded to PITCH=72 (pad = 0). 18*128*72 = 165888 elems, grid 648x256.
// ---------------------------------------------------------------------------
__global__ __launch_bounds__(256) void wt_transpose(const float* __restrict__ w,
                                                    unsigned short* __restrict__ wt) {
    int e  = blockIdx.x * 256 + threadIdx.x;     // [0, 165888)
    int gk = e / (128 * PITCH);
    int r  = e - gk * (128 * PITCH);
    int oc = r / PITCH;
    int c  = r - oc * PITCH;
    int g  = gk / 9, k = gk - g * 9;
    float v = (c < Cgn) ? w[((size_t)oc * Cn + g * Cgn + c) * KKn + k] : 0.f;
    wt[e] = f2bf(v);
}

// ---------------------------------------------------------------------------
// Kernel 0b: pack offset weights: owp[tr][c][28], q = j*9+k (27 used, 1 pad).
// ---------------------------------------------------------------------------
__global__ __launch_bounds__(256) void ow_pack(const float* __restrict__ ow,
                                               float* __restrict__ owp) {
    int e  = blockIdx.x * 256 + threadIdx.x;     // [0, 32256)
    if (e >= 18 * 64 * 28) return;
    int tr = e / (64 * 28);
    int r  = e - tr * (64 * 28);
    int c  = r / 28;
    int q  = r - c * 28;
    float v = 0.f;
    if (q < 27) {
        int j = q / 9, k = q - j * 9;
        int oc = tr * 3 + j;
        v = ow[((size_t)oc * Cgn + c) * KKn + k];
    }
    owp[e] = v;
}

// ---------------------------------------------------------------------------
// Kernel 1: grouped offset conv, 3 oc per block (R3-proven body).
// grid (16, 18, 8), block 256 (4 ho rows). Output bf16.
// ---------------------------------------------------------------------------
__global__ __launch_bounds__(256) void offset_conv(const float* __restrict__ x,
                                                   const float* __restrict__ owp,
                                                   const float* __restrict__ ob,
                                                   unsigned short* __restrict__ om) {
    const int t  = threadIdx.x;
    const int wo = t & 63;
    const int ho = blockIdx.x * 4 + (t >> 6);
    const int tr = blockIdx.y;                   // oc triple 0..17
    const int b  = blockIdx.z;
    const int g  = tr / 9;                       // conv group

    const float* wp = owp + (size_t)tr * 64 * 28;
    float acc0 = ob[tr * 3 + 0];
    float acc1 = ob[tr * 3 + 1];
    float acc2 = ob[tr * 3 + 2];

    const float* xb = x + ((size_t)b * Cn + g * Cgn) * (Hn * Wn);
    const int iy0 = ho - 2, iy1 = ho, iy2 = ho + 2;
    const bool vy0 = iy0 >= 0, vy2 = iy2 < Hn;
    const int ix0 = wo - 2, ix1 = wo, ix2 = wo + 2;
    const bool vx0 = ix0 >= 0, vx2 = ix2 < Wn;

#pragma unroll 2
    for (int c = 0; c < Cgn; ++c) {
        const float* xc = xb + (size_t)c * (Hn * Wn);
        const float* r0 = xc + iy0 * Wn;
        const float* r1 = xc + iy1 * Wn;
        const float* r2 = xc + iy2 * Wn;
        float xv[9];
        xv[0] = (vy0 & vx0) ? r0[ix0] : 0.f;
        xv[1] = vy0         ? r0[ix1] : 0.f;
        xv[2] = (vy0 & vx2) ? r0[ix2] : 0.f;
        xv[3] = vx0         ? r1[ix0] : 0.f;
        xv[4] =               r1[ix1];
        xv[5] = vx2         ? r1[ix2] : 0.f;
        xv[6] = (vy2 & vx0) ? r2[ix0] : 0.f;
        xv[7] = vy2         ? r2[ix1] : 0.f;
        xv[8] = (vy2 & vx2) ? r2[ix2] : 0.f;
        const float* wc = wp + c * 28;
#pragma unroll
        for (int k = 0; k < 9; ++k) acc0 = fmaf(xv[k], wc[k], acc0);
#pragma unroll
        for (int k = 0; k < 9; ++k) acc1 = fmaf(xv[k], wc[9 + k], acc1);
#pragma unroll
        for (int k = 0; k < 9; ++k) acc2 = fmaf(xv[k], wc[18 + k], acc2);
    }
    size_t o = (((size_t)b * 54 + tr * 3) * HOn + ho) * WOn + wo;
    om[o]                     = f2bf(acc0);
    om[o + (size_t)HOn*WOn]   = f2bf(acc1);
    om[o + (size_t)2*HOn*WOn] = f2bf(acc2);
}

// ---------------------------------------------------------------------------
// Kernel 2: fused deformable gather + bf16 MFMA (R3-proven body). Only change
// vs R3: 1-D grid 512 with XCD swizzle b = id & 7 so all 64 blocks of batch b
// land on one XCD -> x[b] (2.1 MB) stays L2-resident.
// LDS: 9216 (val) + 18432 (w) + 18432 (cw) + 4608 (pk) = 50688 -> 3 blk/CU.
// ---------------------------------------------------------------------------
__global__ __launch_bounds__(256, 3) void dcn_main(const float* __restrict__ x,
                                                   const unsigned short* __restrict__ om,
                                                   const unsigned short* __restrict__ wtp,
                                                   float* __restrict__ out) {
    __shared__ __align__(16) unsigned short s_val[64 * PITCH];   // [pos][c]
    __shared__ __align__(16) unsigned short s_w[128 * PITCH];    // [oc][c]
    __shared__ float4 s_cw[18][64];
    __shared__ int    s_pk[18][64];

    const int t  = threadIdx.x;
    const int id = blockIdx.x;               // [0, 512)
    const int b  = id & 7;                   // XCD-aware swizzle
    const int ho = id >> 3;

    // ---- sampling params for all (g,k,wo) of this row ----
    for (int e = t; e < 18 * 64; e += 256) {
        int wo = e & 63;
        int gk = e >> 6;
        int g  = gk / 9, k = gk - g * 9;
        int ky = k / 3,  kx = k - ky * 3;
        const unsigned short* omb = om + (size_t)b * 54 * (HOn * WOn) + ho * WOn + wo;
        float offy = bf2f(omb[(g * 18 + k * 2 + 0) * (HOn * WOn)]);
        float offx = bf2f(omb[(g * 18 + k * 2 + 1) * (HOn * WOn)]);
        float mk   = bf2f(omb[(36 + g * 9 + k) * (HOn * WOn)]);
        mk = 2.0f / (1.0f + __expf(-mk));

        float py = offy + (float)(ky * 2 + ho - 2);
        float px = offx + (float)(kx * 2 + wo - 2);
        float fy = floorf(py), fx = floorf(px);
        int   y0 = (int)fy,    x0 = (int)fx;
        float wy = py - fy,    wx = px - fx;

        bool vy0 = (y0 >= 0) & (y0 < Hn);
        bool vy1 = (y0 + 1 >= 0) & (y0 + 1 < Hn);
        bool vx0 = (x0 >= 0) & (x0 < Wn);
        bool vx1 = (x0 + 1 >= 0) & (x0 + 1 < Wn);
        float4 cw;
        cw.x = (vy0 & vx0) ? (1.f - wy) * (1.f - wx) * mk : 0.f;
        cw.y = (vy0 & vx1) ? (1.f - wy) * wx * mk : 0.f;
        cw.z = (vy1 & vx0) ? wy * (1.f - wx) * mk : 0.f;
        cw.w = (vy1 & vx1) ? wy * wx * mk : 0.f;

        int y0c = min(max(y0, 0), Hn - 1);
        int y1c = min(max(y0 + 1, 0), Hn - 1);
        int x0c = min(max(x0, 0), Wn - 1);
        int x1c = min(max(x0 + 1, 0), Wn - 1);
        s_cw[gk][wo] = cw;
        s_pk[gk][wo] = y0c | (y1c << 8) | (x0c << 16) | (x1c << 24);
    }
    __syncthreads();

    const int lane = t & 63;
    const int wv   = t >> 6;                 // wave id 0..3
    const int lr   = lane & 15;              // MFMA row/col part
    const int lk   = (lane >> 4) * 8;        // MFMA k offset

    f32x4 acc[4][2];
#pragma unroll
    for (int mt = 0; mt < 4; ++mt)
#pragma unroll
        for (int nt = 0; nt < 2; ++nt) acc[mt][nt] = (f32x4){0.f, 0.f, 0.f, 0.f};

    for (int gk = 0; gk < 18; ++gk) {
        if (gk) __syncthreads();

        // ---- weight slab prefetch (global -> regs, written to LDS below) ----
        const int4* wsrc = (const int4*)(wtp + (size_t)gk * 128 * PITCH);
        int4 wreg[5];
#pragma unroll
        for (int i = 0; i < 4; ++i) wreg[i] = wsrc[t + i * 256];
        if (t < 128) wreg[4] = wsrc[t + 1024];

        // ---- gather val tile: lane = pos, this wave covers 16 channels ----
        {
            const int g = gk / 9;
            float4 cw = s_cw[gk][lane];
            int pk = s_pk[gk][lane];
            int y0c = pk & 255, y1c = (pk >> 8) & 255;
            int x0c = (pk >> 16) & 255, x1c = (pk >> 24) & 255;
            int i00 = y0c * Wn + x0c, i01 = y0c * Wn + x1c;
            int i10 = y1c * Wn + x0c, i11 = y1c * Wn + x1c;
            const float* xb = x + ((size_t)(b * Cn + g * Cgn + wv * 16)) * (Hn * Wn);
#pragma unroll
            for (int s = 0; s < 2; ++s) {
                short8 hv;
#pragma unroll
                for (int i = 0; i < 8; ++i) {
                    const float* xc = xb + (size_t)(s * 8 + i) * (Hn * Wn);
                    float v = cw.x * xc[i00] + cw.y * xc[i01] +
                              cw.z * xc[i10] + cw.w * xc[i11];
                    hv[i] = (short)f2bf(v);
                }
                *(short8*)&s_val[lane * PITCH + wv * 16 + s * 8] = hv;
            }
        }
        // ---- commit weight slab to LDS ----
        {
            int4* wdst = (int4*)s_w;
#pragma unroll
            for (int i = 0; i < 4; ++i) wdst[t + i * 256] = wreg[i];
            if (t < 128) wdst[t + 1024] = wreg[4];
        }
        __syncthreads();

        // ---- 2 K-steps of MFMA over the 64-channel tile ----
#pragma unroll
        for (int ks = 0; ks < 2; ++ks) {
            const int k0 = ks * 32;
            short8 af[4], bf[2];
#pragma unroll
            for (int mt = 0; mt < 4; ++mt)
                af[mt] = *(const short8*)&s_val[(mt * 16 + lr) * PITCH + k0 + lk];
#pragma unroll
            for (int nt = 0; nt < 2; ++nt)
                bf[nt] = *(const short8*)&s_w[(wv * 32 + nt * 16 + lr) * PITCH + k0 + lk];
#pragma unroll
            for (int mt = 0; mt < 4; ++mt)
#pragma unroll
                for (int nt = 0; nt < 2; ++nt)
                    acc[mt][nt] = __builtin_amdgcn_mfma_f32_16x16x32_bf16(
                        af[mt], bf[nt], acc[mt][nt], 0, 0, 0);
        }
    }

    // ---- epilogue: D col = oc (lane&15), row = pos ((lane>>4)*4 + reg) ----
#pragma unroll
    for (int mt = 0; mt < 4; ++mt)
#pragma unroll
        for (int nt = 0; nt < 2; ++nt) {
            int oc = wv * 32 + nt * 16 + lr;
            int p0 = mt * 16 + (lane >> 4) * 4;
            float4 v = {acc[mt][nt][0], acc[mt][nt][1], acc[mt][nt][2], acc[mt][nt][3]};
            *(float4*)&out[(((size_t)b * Con + oc) * HOn + ho) * WOn + p0] = v;
        }
}

// ---------------------------------------------------------------------------
extern "C" void kernel_launch(void* const* d_in, const int* in_sizes, int n_in,
                              void* d_out, int out_size, void* d_ws, size_t ws_size,
                              hipStream_t stream) {
    const float* x  = (const float*)d_in[0];   // [8,128,64,64]
    const float* ow = (const float*)d_in[1];   // [54,64,3,3]
    const float* ob = (const float*)d_in[2];   // [54]
    const float* w  = (const float*)d_in[3];   // [128,128,3,3]
    float* out = (float*)d_out;                // [8,128,64,64]

    // workspace: om bf16 (3538944 B) | wt bf16 (331776 B) | owp f32 (129024 B)
    unsigned short* om = (unsigned short*)d_ws;
    unsigned short* wt = (unsigned short*)((char*)d_ws + 3538944);
    float* owp = (float*)((char*)d_ws + 3538944 + 331776);

    hipLaunchKernelGGL(wt_transpose, dim3(648), dim3(256), 0, stream, w, wt);
    hipLaunchKernelGGL(ow_pack, dim3(126), dim3(256), 0, stream, ow, owp);
    hipLaunchKernelGGL(offset_conv, dim3(16, 18, 8), dim3(256), 0, stream,
                       x, owp, ob, om);
    hipLaunchKernelGGL(dcn_main, dim3(512), dim3(256), 0, stream,
                       x, om, wt, out);
}